// Round 3
// baseline (454.701 us; speedup 1.0000x reference)
//
#include <hip/hip_runtime.h>

// out = clip(median7(adv_patch)*contrast + brightness + 0.1*noise, 1e-6, 0.99999)
//   adv_patch [3,300,300], noise [16,14,3,300,300], contrast/brightness [16,14]
// OUTPUT: float32 (R0/R1 forensics: compared buffer is 242MB f32).
// INPUT storage dtype (f32 vs bf16) self-detected per-wave (graph-capture-safe):
//   one uint4/lane from adv_patch + __any(bit15) — bf16 uniform[0,1) can never
//   set bit15; f32 storage has ~256 random mantissa-low bit15s (P_miss ~ 2^-256).
//
// R2: forgetful-selection median (register-resident) — killed 52.7MB scratch spill.
// R3: strided-strip apply (+12us), detect launch removed.
// R4: apply: uint4 bf16 noise loads (16B/lane), nontemporal noise/out traffic,
//     32 elem/thread. median7: 4 pixels/thread via 7x10 register tile (70 loads
//     serve 4 windows, 2.8x fewer load instrs), aligned float4 pmed store.
#define PATCH    300
#define CHW      (PATCH*PATCH)          // 90000
#define NPATCH   (3*CHW)                // 270000
#define NSLAB    (16*14)                // 224
#define G8       (NPATCH/8)             // 33750 8-elem groups (apply, exact)
#define NQ       (NPATCH/4)             // 67500 pixel quads (median, exact)
#define QROW     (PATCH/4)              // 75
#define QCHW     (CHW/4)                // 22500

#define PMED_OFF 0

typedef float        f32x4 __attribute__((ext_vector_type(4)));
typedef unsigned int u32x4 __attribute__((ext_vector_type(4)));

static __device__ __forceinline__ float bf2f(unsigned int bits16) {
    return __uint_as_float(bits16 << 16);
}

// Per-wave dtype probe: first 1KB of adv_patch (L1/L2-resident), wave-uniform.
static __device__ __forceinline__ int detect_f32(const void* patchv) {
    const uint4* p4 = (const uint4*)patchv;
    uint4 v = p4[threadIdx.x & 63];
    return __any(((v.x | v.y | v.z | v.w) & 0x80008000u) != 0u);
}

// compare-swap: x=min, y=max
#define CSWAP(x, y) do { float t_ = fminf(x, y); (y) = fmaxf(x, y); (x) = t_; } while (0)

// Median of a 7x7 window = cols [K, K+6] of a 7x10 register tile, via
// forgetful selection. Working set 26 = 49/2+2: the running min has 25 known
// elements >= it (rank<=24), the running max 25 known <= it (rank>=26);
// neither can be the rank-25 (median) VALUE -> drop both, insert next.
// Window traversal order is irrelevant for the median VALUE. All indices
// compile-time under full unroll => register-resident, no scratch.
template <int K>
static __device__ __forceinline__ float median49_tile(const float (&t)[7][10]) {
    float a[26];
#pragma unroll
    for (int m = 0; m < 26; ++m) a[m] = t[m / 7][K + m % 7];
    float nxt = t[26 / 7][K + 26 % 7];
#pragma unroll
    for (int it = 0; it < 23; ++it) {
#pragma unroll
        for (int i = it + 1; i <= 25; ++i) CSWAP(a[it], a[i]);   // min -> a[it]
#pragma unroll
        for (int i = it + 1; i < 25; ++i)  CSWAP(a[i], a[25]);   // max -> a[25]
        a[25] = nxt;                          // drop min & max, insert next
        if (it < 22) {
            const int m = 27 + it;
            nxt = t[m / 7][K + m % 7];
        }
    }
    float mn = fminf(a[23], a[24]);
    float mx = fmaxf(a[23], a[24]);
    return fmaxf(mn, fminf(mx, a[25]));
}

template <bool F32>
static __device__ __forceinline__ void load_tile(const void* pc, const int* ro,
                                                 const int* cc, float (&t)[7][10]) {
#pragma unroll
    for (int i = 0; i < 7; ++i)
#pragma unroll
        for (int j = 0; j < 10; ++j)
            t[i][j] = F32 ? ((const float*)pc)[ro[i] + cc[j]]
                          : bf2f(((const unsigned short*)pc)[ro[i] + cc[j]]);
}

// 7x7 median, reflect padding. 4 horizontal pixels/thread sharing one 7x10
// register tile; aligned float4 store (PATCH=300 => rows are 4-aligned).
__global__ __launch_bounds__(256) void median7_kernel(
        const void* __restrict__ patchv,
        float* __restrict__ pmed) {
    int mode = detect_f32(patchv);           // wave-uniform, before any return
    int q = blockIdx.x * 256 + threadIdx.x;  // pixel-quad index
    if (q >= NQ) return;
    int c   = q / QCHW;
    int rem = q - c * QCHW;
    int h   = rem / QROW;
    int w0  = (rem - h * QROW) * 4;

    int ro[7], cc[10];
#pragma unroll
    for (int d = 0; d < 7; ++d) {
        int x = h + d - 3;                   // reflect (no edge duplication)
        x = x < 0 ? -x : (x >= PATCH ? 2 * PATCH - 2 - x : x);
        ro[d] = x * PATCH;
    }
#pragma unroll
    for (int d = 0; d < 10; ++d) {
        int y = w0 + d - 3;
        cc[d] = y < 0 ? -y : (y >= PATCH ? 2 * PATCH - 2 - y : y);
    }

    float t[7][10];
    if (mode) load_tile<true >((const void*)((const float*)patchv + c * CHW), ro, cc, t);
    else      load_tile<false>((const void*)((const unsigned short*)patchv + c * CHW), ro, cc, t);

    f32x4 r;
    r[0] = median49_tile<0>(t);
    r[1] = median49_tile<1>(t);
    r[2] = median49_tile<2>(t);
    r[3] = median49_tile<3>(t);
    ((f32x4*)pmed)[q] = r;
}

#define CLIP1(p, n) fminf(fmaxf((p) * c + br + (n) * 0.1f, 1e-6f), 0.99999f)

// out[slab, e] = clip(pmed[e]*c[slab] + br[slab] + 0.1*noise[slab,e]) (f32 out)
// 32 elements/thread as 4 block-strided 8-elem strips. bf16 noise loads are
// uint4 (16B/lane, 1KB/instruction). noise loads + out stores are nontemporal
// (streamed once; keep L2 for pmed). slab on blockIdx.y.
__global__ __launch_bounds__(256) void apply_kernel(
        const float* __restrict__ pmed,
        const void* __restrict__ patchv,     // dtype probe only
        const void* __restrict__ noisev,
        const void* __restrict__ contrastv,
        const void* __restrict__ brightnessv,
        float* __restrict__ out) {
    int mode = detect_f32(patchv);           // wave-uniform, full wave active
    int slab = blockIdx.y;
    int j0   = blockIdx.x * 1024 + threadIdx.x;   // 8-elem group, strip 0

    float c, br;
    if (mode) {
        c  = ((const float*)contrastv)[slab];
        br = ((const float*)brightnessv)[slab];
    } else {
        c  = bf2f(((const unsigned short*)contrastv)[slab]);
        br = bf2f(((const unsigned short*)brightnessv)[slab]);
    }

    const f32x4* pm4 = (const f32x4*)pmed;
    f32x4*       o4  = (f32x4*)out + (size_t)slab * (2 * G8);
    bool full = (j0 + 3 * 256) < G8;

    if (mode) {          // ---- f32 noise ----
        const f32x4* n4 = (const f32x4*)noisev + (size_t)slab * (2 * G8);
#pragma unroll
        for (int k = 0; k < 4; ++k) {
            int j = j0 + k * 256;
            if (full || j < G8) {
                f32x4 pa = pm4[2 * j], pb = pm4[2 * j + 1];
                f32x4 na = __builtin_nontemporal_load(&n4[2 * j]);
                f32x4 nb = __builtin_nontemporal_load(&n4[2 * j + 1]);
                f32x4 ra, rb;
#pragma unroll
                for (int i = 0; i < 4; ++i) {
                    ra[i] = CLIP1(pa[i], na[i]);
                    rb[i] = CLIP1(pb[i], nb[i]);
                }
                __builtin_nontemporal_store(ra, &o4[2 * j]);
                __builtin_nontemporal_store(rb, &o4[2 * j + 1]);
            }
        }
    } else {             // ---- bf16 noise ----
        const u32x4* n4 = (const u32x4*)noisev + (size_t)slab * G8;  // 8 bf16
#pragma unroll
        for (int k = 0; k < 4; ++k) {
            int j = j0 + k * 256;
            if (full || j < G8) {
                f32x4 pa = pm4[2 * j], pb = pm4[2 * j + 1];
                u32x4 nv = __builtin_nontemporal_load(&n4[j]);
                f32x4 ra, rb;
                ra[0] = CLIP1(pa[0], bf2f(nv[0] & 0xffffu));
                ra[1] = CLIP1(pa[1], bf2f(nv[0] >> 16));
                ra[2] = CLIP1(pa[2], bf2f(nv[1] & 0xffffu));
                ra[3] = CLIP1(pa[3], bf2f(nv[1] >> 16));
                rb[0] = CLIP1(pb[0], bf2f(nv[2] & 0xffffu));
                rb[1] = CLIP1(pb[1], bf2f(nv[2] >> 16));
                rb[2] = CLIP1(pb[2], bf2f(nv[3] & 0xffffu));
                rb[3] = CLIP1(pb[3], bf2f(nv[3] >> 16));
                __builtin_nontemporal_store(ra, &o4[2 * j]);
                __builtin_nontemporal_store(rb, &o4[2 * j + 1]);
            }
        }
    }
}

extern "C" void kernel_launch(void* const* d_in, const int* in_sizes, int n_in,
                              void* d_out, int out_size, void* d_ws, size_t ws_size,
                              hipStream_t stream) {
    const void* adv_patch  = d_in[0];
    // d_in[1] = lab_batch (unused by the math)
    const void* contrast   = d_in[2];
    const void* brightness = d_in[3];
    const void* noise      = d_in[4];
    // d_in[5] = img_size (unused)

    float* pmed = (float*)((char*)d_ws + PMED_OFF);   // NPATCH f32 ~= 1.03 MB
    float* out  = (float*)d_out;

    median7_kernel<<<dim3((NQ + 255) / 256), dim3(256), 0, stream>>>(
        adv_patch, pmed);

    dim3 g2((G8 + 1023) / 1024, NSLAB);
    apply_kernel<<<g2, dim3(256), 0, stream>>>(
        pmed, adv_patch, noise, contrast, brightness, out);
}

// Round 4
// 439.049 us; speedup vs baseline: 1.0357x; 1.0357x over previous
//
#include <hip/hip_runtime.h>

// out = clip(median7(adv_patch)*contrast + brightness + 0.1*noise, 1e-6, 0.99999)
//   adv_patch [3,300,300], noise [16,14,3,300,300], contrast/brightness [16,14]
// OUTPUT: float32 (R0/R1 forensics: compared buffer is 242MB f32).
// INPUT storage dtype (f32 vs bf16) self-detected per-wave (graph-capture-safe):
//   one uint4/lane from adv_patch + __any(bit15) — bf16 uniform[0,1) can never
//   set bit15; f32 storage has ~256 random mantissa-low bit15s (P_miss ~ 2^-256).
//   NOTE: harness VARIES device input dtype across runs (R0-R2 absmax=2^-8
//   => bf16; R3 absmax=0.0 => f32). f32 runs carry ~+19us apply floor.
//
// R2: forgetful-selection median (register-resident) — killed 52.7MB scratch spill.
// R3: strided-strip apply (+12us), detect launch removed.
// R4: uint4 bf16 noise loads (16B/lane), 32 elem/thread, 4-pixel median via
//     7x10 register tile (2.8x fewer load instrs), nontemporal accesses.
// R5: REVERT nontemporal (R3's unexplained ~-19us residue; its L2-preservation
//     rationale was void — pmed is 1MB and L2-resident regardless). Keep rest.
#define PATCH    300
#define CHW      (PATCH*PATCH)          // 90000
#define NPATCH   (3*CHW)                // 270000
#define NSLAB    (16*14)                // 224
#define G8       (NPATCH/8)             // 33750 8-elem groups (apply, exact)
#define NQ       (NPATCH/4)             // 67500 pixel quads (median, exact)
#define QROW     (PATCH/4)              // 75
#define QCHW     (CHW/4)                // 22500

#define PMED_OFF 0

typedef float        f32x4 __attribute__((ext_vector_type(4)));
typedef unsigned int u32x4 __attribute__((ext_vector_type(4)));

static __device__ __forceinline__ float bf2f(unsigned int bits16) {
    return __uint_as_float(bits16 << 16);
}

// Per-wave dtype probe: first 1KB of adv_patch (L1/L2-resident), wave-uniform.
static __device__ __forceinline__ int detect_f32(const void* patchv) {
    const uint4* p4 = (const uint4*)patchv;
    uint4 v = p4[threadIdx.x & 63];
    return __any(((v.x | v.y | v.z | v.w) & 0x80008000u) != 0u);
}

// compare-swap: x=min, y=max
#define CSWAP(x, y) do { float t_ = fminf(x, y); (y) = fmaxf(x, y); (x) = t_; } while (0)

// Median of a 7x7 window = cols [K, K+6] of a 7x10 register tile, via
// forgetful selection. Working set 26 = 49/2+2: the running min has 25 known
// elements >= it (rank<=24), the running max 25 known <= it (rank>=26);
// neither can be the rank-25 (median) VALUE -> drop both, insert next.
// Window traversal order is irrelevant for the median VALUE. All indices
// compile-time under full unroll => register-resident, no scratch.
template <int K>
static __device__ __forceinline__ float median49_tile(const float (&t)[7][10]) {
    float a[26];
#pragma unroll
    for (int m = 0; m < 26; ++m) a[m] = t[m / 7][K + m % 7];
    float nxt = t[26 / 7][K + 26 % 7];
#pragma unroll
    for (int it = 0; it < 23; ++it) {
#pragma unroll
        for (int i = it + 1; i <= 25; ++i) CSWAP(a[it], a[i]);   // min -> a[it]
#pragma unroll
        for (int i = it + 1; i < 25; ++i)  CSWAP(a[i], a[25]);   // max -> a[25]
        a[25] = nxt;                          // drop min & max, insert next
        if (it < 22) {
            const int m = 27 + it;
            nxt = t[m / 7][K + m % 7];
        }
    }
    float mn = fminf(a[23], a[24]);
    float mx = fmaxf(a[23], a[24]);
    return fmaxf(mn, fminf(mx, a[25]));
}

template <bool F32>
static __device__ __forceinline__ void load_tile(const void* pc, const int* ro,
                                                 const int* cc, float (&t)[7][10]) {
#pragma unroll
    for (int i = 0; i < 7; ++i)
#pragma unroll
        for (int j = 0; j < 10; ++j)
            t[i][j] = F32 ? ((const float*)pc)[ro[i] + cc[j]]
                          : bf2f(((const unsigned short*)pc)[ro[i] + cc[j]]);
}

// 7x7 median, reflect padding. 4 horizontal pixels/thread sharing one 7x10
// register tile; aligned float4 store (PATCH=300 => rows are 4-aligned).
__global__ __launch_bounds__(256) void median7_kernel(
        const void* __restrict__ patchv,
        float* __restrict__ pmed) {
    int mode = detect_f32(patchv);           // wave-uniform, before any return
    int q = blockIdx.x * 256 + threadIdx.x;  // pixel-quad index
    if (q >= NQ) return;
    int c   = q / QCHW;
    int rem = q - c * QCHW;
    int h   = rem / QROW;
    int w0  = (rem - h * QROW) * 4;

    int ro[7], cc[10];
#pragma unroll
    for (int d = 0; d < 7; ++d) {
        int x = h + d - 3;                   // reflect (no edge duplication)
        x = x < 0 ? -x : (x >= PATCH ? 2 * PATCH - 2 - x : x);
        ro[d] = x * PATCH;
    }
#pragma unroll
    for (int d = 0; d < 10; ++d) {
        int y = w0 + d - 3;
        cc[d] = y < 0 ? -y : (y >= PATCH ? 2 * PATCH - 2 - y : y);
    }

    float t[7][10];
    if (mode) load_tile<true >((const void*)((const float*)patchv + c * CHW), ro, cc, t);
    else      load_tile<false>((const void*)((const unsigned short*)patchv + c * CHW), ro, cc, t);

    f32x4 r;
    r[0] = median49_tile<0>(t);
    r[1] = median49_tile<1>(t);
    r[2] = median49_tile<2>(t);
    r[3] = median49_tile<3>(t);
    ((f32x4*)pmed)[q] = r;
}

#define CLIP1(p, n) fminf(fmaxf((p) * c + br + (n) * 0.1f, 1e-6f), 0.99999f)

// out[slab, e] = clip(pmed[e]*c[slab] + br[slab] + 0.1*noise[slab,e]) (f32 out)
// 32 elements/thread as 4 block-strided 8-elem strips. bf16 noise loads are
// uint4 (16B/lane, 1KB/instruction). Plain (cached) loads/stores — NT reverted.
// slab on blockIdx.y.
__global__ __launch_bounds__(256) void apply_kernel(
        const float* __restrict__ pmed,
        const void* __restrict__ patchv,     // dtype probe only
        const void* __restrict__ noisev,
        const void* __restrict__ contrastv,
        const void* __restrict__ brightnessv,
        float* __restrict__ out) {
    int mode = detect_f32(patchv);           // wave-uniform, full wave active
    int slab = blockIdx.y;
    int j0   = blockIdx.x * 1024 + threadIdx.x;   // 8-elem group, strip 0

    float c, br;
    if (mode) {
        c  = ((const float*)contrastv)[slab];
        br = ((const float*)brightnessv)[slab];
    } else {
        c  = bf2f(((const unsigned short*)contrastv)[slab]);
        br = bf2f(((const unsigned short*)brightnessv)[slab]);
    }

    const f32x4* pm4 = (const f32x4*)pmed;
    f32x4*       o4  = (f32x4*)out + (size_t)slab * (2 * G8);
    bool full = (j0 + 3 * 256) < G8;

    if (mode) {          // ---- f32 noise ----
        const f32x4* n4 = (const f32x4*)noisev + (size_t)slab * (2 * G8);
#pragma unroll
        for (int k = 0; k < 4; ++k) {
            int j = j0 + k * 256;
            if (full || j < G8) {
                f32x4 pa = pm4[2 * j], pb = pm4[2 * j + 1];
                f32x4 na = n4[2 * j];
                f32x4 nb = n4[2 * j + 1];
                f32x4 ra, rb;
#pragma unroll
                for (int i = 0; i < 4; ++i) {
                    ra[i] = CLIP1(pa[i], na[i]);
                    rb[i] = CLIP1(pb[i], nb[i]);
                }
                o4[2 * j]     = ra;
                o4[2 * j + 1] = rb;
            }
        }
    } else {             // ---- bf16 noise ----
        const u32x4* n4 = (const u32x4*)noisev + (size_t)slab * G8;  // 8 bf16
#pragma unroll
        for (int k = 0; k < 4; ++k) {
            int j = j0 + k * 256;
            if (full || j < G8) {
                f32x4 pa = pm4[2 * j], pb = pm4[2 * j + 1];
                u32x4 nv = n4[j];
                f32x4 ra, rb;
                ra[0] = CLIP1(pa[0], bf2f(nv[0] & 0xffffu));
                ra[1] = CLIP1(pa[1], bf2f(nv[0] >> 16));
                ra[2] = CLIP1(pa[2], bf2f(nv[1] & 0xffffu));
                ra[3] = CLIP1(pa[3], bf2f(nv[1] >> 16));
                rb[0] = CLIP1(pb[0], bf2f(nv[2] & 0xffffu));
                rb[1] = CLIP1(pb[1], bf2f(nv[2] >> 16));
                rb[2] = CLIP1(pb[2], bf2f(nv[3] & 0xffffu));
                rb[3] = CLIP1(pb[3], bf2f(nv[3] >> 16));
                o4[2 * j]     = ra;
                o4[2 * j + 1] = rb;
            }
        }
    }
}

extern "C" void kernel_launch(void* const* d_in, const int* in_sizes, int n_in,
                              void* d_out, int out_size, void* d_ws, size_t ws_size,
                              hipStream_t stream) {
    const void* adv_patch  = d_in[0];
    // d_in[1] = lab_batch (unused by the math)
    const void* contrast   = d_in[2];
    const void* brightness = d_in[3];
    const void* noise      = d_in[4];
    // d_in[5] = img_size (unused)

    float* pmed = (float*)((char*)d_ws + PMED_OFF);   // NPATCH f32 ~= 1.03 MB
    float* out  = (float*)d_out;

    median7_kernel<<<dim3((NQ + 255) / 256), dim3(256), 0, stream>>>(
        adv_patch, pmed);

    dim3 g2((G8 + 1023) / 1024, NSLAB);
    apply_kernel<<<g2, dim3(256), 0, stream>>>(
        pmed, adv_patch, noise, contrast, brightness, out);
}

// Round 5
// 425.012 us; speedup vs baseline: 1.0699x; 1.0330x over previous
//
#include <hip/hip_runtime.h>

// out = clip(median7(adv_patch)*contrast + brightness + 0.1*noise, 1e-6, 0.99999)
//   adv_patch [3,300,300], noise [16,14,3,300,300], contrast/brightness [16,14]
// OUTPUT: float32 (R0/R1 forensics: compared buffer is 242MB f32).
// INPUT storage dtype (f32 vs bf16) self-detected per-wave (graph-capture-safe):
//   one uint4/lane from adv_patch + __any(bit15) — bf16 uniform[0,1) can never
//   set bit15; f32 storage has ~256 random mantissa-low bit15s (P_miss ~ 2^-256).
//   NOTE: harness VARIES device input dtype across runs (R0-R2 absmax=2^-8
//   => bf16; R3/R4 absmax=0.0 => f32). f32 runs carry ~+19us apply floor.
//
// R2: forgetful-selection median (register-resident) — killed 52.7MB scratch spill.
// R3: dense-strip apply (+11.6us measured), detect launch removed.
// R4: u32x4 noise groups — MISTAKE: silently reverted pmed/out (and f32 noise)
//     to 50%-density 2j/2j+1 interleave. +NT (regressed, reverted in R5).
// R6 (this): apply back to FULLY dense strips, widened to 8 strips/thread with
//     all loads batched before compute (2x in-flight reads per wave; read
//     latency-hiding needs ~4.6KB/CU in flight at 12GB/s/CU read demand).
#define PATCH    300
#define CHW      (PATCH*PATCH)          // 90000
#define NPATCH   (3*CHW)                // 270000
#define NSLAB    (16*14)                // 224
#define NQ       (NPATCH/4)             // 67500 pixel quads / f32x4 groups (exact)
#define QROW     (PATCH/4)              // 75
#define QCHW     (CHW/4)                // 22500

#define PMED_OFF 0

typedef float        f32x4 __attribute__((ext_vector_type(4)));

static __device__ __forceinline__ float bf2f(unsigned int bits16) {
    return __uint_as_float(bits16 << 16);
}

// Per-wave dtype probe: first 1KB of adv_patch (L1/L2-resident), wave-uniform.
static __device__ __forceinline__ int detect_f32(const void* patchv) {
    const uint4* p4 = (const uint4*)patchv;
    uint4 v = p4[threadIdx.x & 63];
    return __any(((v.x | v.y | v.z | v.w) & 0x80008000u) != 0u);
}

// compare-swap: x=min, y=max
#define CSWAP(x, y) do { float t_ = fminf(x, y); (y) = fmaxf(x, y); (x) = t_; } while (0)

// Median of a 7x7 window = cols [K, K+6] of a 7x10 register tile, via
// forgetful selection. Working set 26 = 49/2+2: the running min has 25 known
// elements >= it (rank<=24), the running max 25 known <= it (rank>=26);
// neither can be the rank-25 (median) VALUE -> drop both, insert next.
// Window traversal order is irrelevant for the median VALUE. All indices
// compile-time under full unroll => register-resident, no scratch.
template <int K>
static __device__ __forceinline__ float median49_tile(const float (&t)[7][10]) {
    float a[26];
#pragma unroll
    for (int m = 0; m < 26; ++m) a[m] = t[m / 7][K + m % 7];
    float nxt = t[26 / 7][K + 26 % 7];
#pragma unroll
    for (int it = 0; it < 23; ++it) {
#pragma unroll
        for (int i = it + 1; i <= 25; ++i) CSWAP(a[it], a[i]);   // min -> a[it]
#pragma unroll
        for (int i = it + 1; i < 25; ++i)  CSWAP(a[i], a[25]);   // max -> a[25]
        a[25] = nxt;                          // drop min & max, insert next
        if (it < 22) {
            const int m = 27 + it;
            nxt = t[m / 7][K + m % 7];
        }
    }
    float mn = fminf(a[23], a[24]);
    float mx = fmaxf(a[23], a[24]);
    return fmaxf(mn, fminf(mx, a[25]));
}

template <bool F32>
static __device__ __forceinline__ void load_tile(const void* pc, const int* ro,
                                                 const int* cc, float (&t)[7][10]) {
#pragma unroll
    for (int i = 0; i < 7; ++i)
#pragma unroll
        for (int j = 0; j < 10; ++j)
            t[i][j] = F32 ? ((const float*)pc)[ro[i] + cc[j]]
                          : bf2f(((const unsigned short*)pc)[ro[i] + cc[j]]);
}

// 7x7 median, reflect padding. 4 horizontal pixels/thread sharing one 7x10
// register tile; aligned float4 store (PATCH=300 => rows are 4-aligned).
__global__ __launch_bounds__(256) void median7_kernel(
        const void* __restrict__ patchv,
        float* __restrict__ pmed) {
    int mode = detect_f32(patchv);           // wave-uniform, before any return
    int q = blockIdx.x * 256 + threadIdx.x;  // pixel-quad index
    if (q >= NQ) return;
    int c   = q / QCHW;
    int rem = q - c * QCHW;
    int h   = rem / QROW;
    int w0  = (rem - h * QROW) * 4;

    int ro[7], cc[10];
#pragma unroll
    for (int d = 0; d < 7; ++d) {
        int x = h + d - 3;                   // reflect (no edge duplication)
        x = x < 0 ? -x : (x >= PATCH ? 2 * PATCH - 2 - x : x);
        ro[d] = x * PATCH;
    }
#pragma unroll
    for (int d = 0; d < 10; ++d) {
        int y = w0 + d - 3;
        cc[d] = y < 0 ? -y : (y >= PATCH ? 2 * PATCH - 2 - y : y);
    }

    float t[7][10];
    if (mode) load_tile<true >((const void*)((const float*)patchv + c * CHW), ro, cc, t);
    else      load_tile<false>((const void*)((const unsigned short*)patchv + c * CHW), ro, cc, t);

    f32x4 r;
    r[0] = median49_tile<0>(t);
    r[1] = median49_tile<1>(t);
    r[2] = median49_tile<2>(t);
    r[3] = median49_tile<3>(t);
    ((f32x4*)pmed)[q] = r;
}

#define CLIP1(p, n) fminf(fmaxf((p) * c + br + (n) * 0.1f, 1e-6f), 0.99999f)

// out[slab, e] = clip(pmed[e]*c[slab] + br[slab] + 0.1*noise[slab,e]) (f32 out)
// 8 dense strips of one f32x4-quad per thread (32 elems). ALL memory
// instructions are base + k*256 + tid => 64 lanes x contiguous (100% density):
// pmed loads, noise loads (f32: f32x4 16B/lane; bf16: uint2 8B/lane), stores.
// Loads batched before compute: 16 (f32) / 16 (8pm+8n) outstanding reads per
// thread for HBM latency hiding. slab on blockIdx.y.
__global__ __launch_bounds__(256) void apply_kernel(
        const float* __restrict__ pmed,
        const void* __restrict__ patchv,     // dtype probe only
        const void* __restrict__ noisev,
        const void* __restrict__ contrastv,
        const void* __restrict__ brightnessv,
        float* __restrict__ out) {
    int mode = detect_f32(patchv);           // wave-uniform, full wave active
    int slab = blockIdx.y;
    int q0   = blockIdx.x * 2048 + threadIdx.x;   // quad index, strip 0

    float c, br;
    if (mode) {
        c  = ((const float*)contrastv)[slab];
        br = ((const float*)brightnessv)[slab];
    } else {
        c  = bf2f(((const unsigned short*)contrastv)[slab]);
        br = bf2f(((const unsigned short*)brightnessv)[slab]);
    }

    const f32x4* pm4 = (const f32x4*)pmed;
    f32x4*       o4  = (f32x4*)out + (size_t)slab * NQ;
    bool full = (q0 + 7 * 256) < NQ;

    if (mode) {          // ---- f32 noise ----
        const f32x4* n4 = (const f32x4*)noisev + (size_t)slab * NQ;
        if (full) {
            f32x4 p[8], n[8];
#pragma unroll
            for (int k = 0; k < 8; ++k) p[k] = pm4[q0 + k * 256];
#pragma unroll
            for (int k = 0; k < 8; ++k) n[k] = n4[q0 + k * 256];
#pragma unroll
            for (int k = 0; k < 8; ++k) {
                f32x4 r;
#pragma unroll
                for (int i = 0; i < 4; ++i) r[i] = CLIP1(p[k][i], n[k][i]);
                o4[q0 + k * 256] = r;
            }
        } else {
#pragma unroll
            for (int k = 0; k < 8; ++k) {
                int q = q0 + k * 256;
                if (q < NQ) {
                    f32x4 p = pm4[q], n = n4[q], r;
#pragma unroll
                    for (int i = 0; i < 4; ++i) r[i] = CLIP1(p[i], n[i]);
                    o4[q] = r;
                }
            }
        }
    } else {             // ---- bf16 noise (uint2 = 4 bf16 per quad) ----
        const uint2* n2 = (const uint2*)noisev + (size_t)slab * NQ;
        if (full) {
            f32x4 p[8];
            uint2 nv[8];
#pragma unroll
            for (int k = 0; k < 8; ++k) p[k]  = pm4[q0 + k * 256];
#pragma unroll
            for (int k = 0; k < 8; ++k) nv[k] = n2[q0 + k * 256];
#pragma unroll
            for (int k = 0; k < 8; ++k) {
                f32x4 r;
                r[0] = CLIP1(p[k][0], bf2f(nv[k].x & 0xffffu));
                r[1] = CLIP1(p[k][1], bf2f(nv[k].x >> 16));
                r[2] = CLIP1(p[k][2], bf2f(nv[k].y & 0xffffu));
                r[3] = CLIP1(p[k][3], bf2f(nv[k].y >> 16));
                o4[q0 + k * 256] = r;
            }
        } else {
#pragma unroll
            for (int k = 0; k < 8; ++k) {
                int q = q0 + k * 256;
                if (q < NQ) {
                    f32x4 p = pm4[q], r;
                    uint2 nv = n2[q];
                    r[0] = CLIP1(p[0], bf2f(nv.x & 0xffffu));
                    r[1] = CLIP1(p[1], bf2f(nv.x >> 16));
                    r[2] = CLIP1(p[2], bf2f(nv.y & 0xffffu));
                    r[3] = CLIP1(p[3], bf2f(nv.y >> 16));
                    o4[q] = r;
                }
            }
        }
    }
}

extern "C" void kernel_launch(void* const* d_in, const int* in_sizes, int n_in,
                              void* d_out, int out_size, void* d_ws, size_t ws_size,
                              hipStream_t stream) {
    const void* adv_patch  = d_in[0];
    // d_in[1] = lab_batch (unused by the math)
    const void* contrast   = d_in[2];
    const void* brightness = d_in[3];
    const void* noise      = d_in[4];
    // d_in[5] = img_size (unused)

    float* pmed = (float*)((char*)d_ws + PMED_OFF);   // NPATCH f32 ~= 1.03 MB
    float* out  = (float*)d_out;

    median7_kernel<<<dim3((NQ + 255) / 256), dim3(256), 0, stream>>>(
        adv_patch, pmed);

    dim3 g2((NQ + 2047) / 2048, NSLAB);
    apply_kernel<<<g2, dim3(256), 0, stream>>>(
        pmed, adv_patch, noise, contrast, brightness, out);
}